// Round 8
// baseline (257.236 us; speedup 1.0000x reference)
//
#include <hip/hip_runtime.h>

// PartialMatchingLoss: mean over (b,m) of min_n ||partial[b,m] - completed[b,n]||
// B=8, M=4096 (partial), N=8192 (completed), D=3, fp32.
//
// R13: single-wave pruned NN, scalar-pipe candidates.
// R12 post-mortem: occupancy 9% (2 fat blocks/CU, no backfill), 4x-redundant
// LDS rescans behind __syncthreads, prep histogramming 4x redundantly.
// Now: 512 blocks x 1 wave; lane = query (64 sorted queries/wave -> shared
// window); window bounds wave-uniform (butterfly + readfirstlane -> SGPR) so
// candidate loads are uniform-address -> s_load_dwordx16 (4 cand/instr, free
// broadcast, no LDS, no barriers). Per candidate: 3 fmaf + min = the floor.
// Two-phase exactness (validated absmax 0.0 in R10/R11/R12):
//   phase 1: bins [binOf(xL)-1, binOf(xR)+1] -> per-lane d_ub (lane = query).
//   phase 2: md = wave max d_ub; extend to binOf(xL-md)..binOf(xR+md).
//   Excluded c: |x_c - x_q| > md >= d_ub(q) >= d(q). Empty-window -> md=inf
//   -> full scan (binOf saturates on +/-inf). Exact.
// Prep: 2 kernels, 8 slices per (batch,set): A) per-slice LDS histogram
// (1/8th the per-CU atomic load) -> global; B) scan + slice scatter.

constexpr int B  = 8;
constexpr int N  = 8192;
constexpr int M  = 4096;
constexpr int NB = 256;                       // x-bins per batch
constexpr float XLO = -6.0f, XHI = 6.0f;      // N(0,1): no sample near +/-6
constexpr float BINV = (float)NB / (XHI - XLO);
constexpr int ROWS = B * M;                   // 32768
constexpr int SLICES = 8;
constexpr float FMAX = 3.402823466e38f;

// ws: cStart[8][257] | cPk f4[8][8192] | qPk f4[8][4096] | hist[16][8][256]
constexpr size_t OFF_CPK  = 16 * 1024;
constexpr size_t OFF_QPK  = OFF_CPK + (size_t)B * N * 16;
constexpr size_t OFF_HIST = OFF_QPK + (size_t)B * M * 16;

__device__ __forceinline__ int binOf(float x) {
    int k = (int)floorf((x - XLO) * BINV);    // v_cvt saturates on +/-inf
    return k < 0 ? 0 : (k > NB - 1 ? NB - 1 : k);
}

// ---- prepA: per-slice histogram -> global ----------------------------------
__global__ __launch_bounds__(256) void pml_prepA(const float* __restrict__ completed,
                                                 const float* __restrict__ partial,
                                                 int* __restrict__ hist,
                                                 float* __restrict__ out) {
    __shared__ int cnt[NB];
    const int t     = threadIdx.x;
    const int role  = blockIdx.x >> 3;        // 0..15 = (b, set)
    const int slice = blockIdx.x & 7;
    const int b     = role >> 1;
    const bool isQ  = role & 1;
    const int ns    = (isQ ? M : N) / SLICES; // 512 / 1024
    const float* src = (isQ ? partial + (size_t)b * M * 3
                            : completed + (size_t)b * N * 3) + (size_t)slice * ns * 3;

    cnt[t] = 0;
    __syncthreads();
    for (int i = t; i < ns; i += 256)
        atomicAdd(&cnt[binOf(src[3 * i])], 1);
    __syncthreads();
    hist[(size_t)blockIdx.x * NB + t] = cnt[t];
    if (blockIdx.x == 0 && t == 0) out[0] = 0.0f;   // main runs strictly after
}

// ---- prepB: scan (from slice hists) + scatter own slice --------------------
__global__ __launch_bounds__(256) void pml_prepB(const float* __restrict__ completed,
                                                 const float* __restrict__ partial,
                                                 const int* __restrict__ hist,
                                                 int* __restrict__ cStart,
                                                 float4* __restrict__ cPk,
                                                 float4* __restrict__ qPk) {
    __shared__ int sc[NB];
    __shared__ int st[NB + 1];
    __shared__ int mybase[NB];
    __shared__ int cur[NB];
    const int t     = threadIdx.x;
    const int role  = blockIdx.x >> 3;
    const int slice = blockIdx.x & 7;
    const int b     = role >> 1;
    const bool isQ  = role & 1;
    const int ns    = (isQ ? M : N) / SLICES;
    const float* src = (isQ ? partial + (size_t)b * M * 3
                            : completed + (size_t)b * N * 3) + (size_t)slice * ns * 3;

    int tot = 0, pre = 0;
#pragma unroll
    for (int s = 0; s < SLICES; ++s) {
        int h = hist[(size_t)((role << 3) + s) * NB + t];
        tot += h;
        if (s < slice) pre += h;
    }
    sc[t] = tot;
    __syncthreads();
#pragma unroll
    for (int o = 1; o < NB; o <<= 1) {        // Hillis-Steele inclusive scan
        int v = sc[t];
        if (t >= o) v += sc[t - o];
        __syncthreads();
        sc[t] = v;
        __syncthreads();
    }
    st[t + 1] = sc[t];
    if (t == 0) st[0] = 0;
    __syncthreads();
    if (!isQ && slice == 0)
        for (int k = t; k <= NB; k += 256) cStart[b * (NB + 1) + k] = st[k];
    mybase[t] = st[t] + pre;
    cur[t] = 0;
    __syncthreads();

    float4* dst = isQ ? qPk + (size_t)b * M : cPk + (size_t)b * N;
    for (int i = t; i < ns; i += 256) {
        float x = src[3 * i], y = src[3 * i + 1], z = src[3 * i + 2];
        int k = binOf(x);
        int pos = mybase[k] + atomicAdd(&cur[k], 1);
        float q2 = x * x + y * y + z * z;
        dst[pos] = make_float4(x, y, z, isQ ? q2 : 0.5f * q2);
    }
}

// ---- main: 1 wave/block, lane = query, SMEM-broadcast candidates -----------
constexpr int QPB = 64;
constexpr int MAIN_BLOCKS = ROWS / QPB;       // 512
constexpr int BPB = M / QPB;                  // 64 blocks per batch

__global__ __launch_bounds__(64) void pml_main(const int* __restrict__ cStart,
                                               const float4* __restrict__ cPk,
                                               const float4* __restrict__ qPk,
                                               float* __restrict__ out) {
    const int lane = threadIdx.x;
    const int b    = blockIdx.x / BPB;
    const int q    = (blockIdx.x % BPB) * QPB + lane;

    const float4 Q = qPk[(size_t)b * M + q];
    const float px = -Q.x, py = -Q.y, pz = -Q.z, psq = Q.w;
    const int* bs = cStart + b * (NB + 1);
    const float4* cb = cPk + (size_t)b * N;

    // wave x-extremes (uniform after full butterfly)
    float xmn = Q.x, xmx = Q.x;
#pragma unroll
    for (int o = 1; o < 64; o <<= 1) {
        xmn = fminf(xmn, __shfl_xor(xmn, o));
        xmx = fmaxf(xmx, __shfl_xor(xmx, o));
    }
    const float xL = xmn, xR = xmx;

    const int l0 = __builtin_amdgcn_readfirstlane(max(binOf(xL) - 1, 0));
    const int r0 = __builtin_amdgcn_readfirstlane(min(binOf(xR) + 1, NB - 1));
    const int lo = bs[l0], hi = bs[r0 + 1];

    float best = FMAX;
    // Uniform-address scan: bounds forced to SGPR -> s_load_dwordx16 stream.
    auto scan = [&](int lo_, int hi_) {
        lo_ = __builtin_amdgcn_readfirstlane(lo_);
        hi_ = __builtin_amdgcn_readfirstlane(hi_);
        const int n = hi_ - lo_;
        const float4* p = cb + lo_;
        int i = 0;
#pragma unroll 2
        for (; i + 4 <= n; i += 4) {
            float4 c0 = p[i], c1 = p[i + 1], c2 = p[i + 2], c3 = p[i + 3];
            float f0 = fmaf(px, c0.x, fmaf(py, c0.y, fmaf(pz, c0.z, c0.w)));
            float f1 = fmaf(px, c1.x, fmaf(py, c1.y, fmaf(pz, c1.z, c1.w)));
            float f2 = fmaf(px, c2.x, fmaf(py, c2.y, fmaf(pz, c2.z, c2.w)));
            float f3 = fmaf(px, c3.x, fmaf(py, c3.y, fmaf(pz, c3.z, c3.w)));
            best = fminf(best, fminf(f0, f1));     // v_min3_f32
            best = fminf(best, fminf(f2, f3));
        }
        for (; i < n; ++i) {                       // uniform tail, <=3 iters
            float4 c = p[i];
            best = fminf(best, fmaf(px, c.x, fmaf(py, c.y, fmaf(pz, c.z, c.w))));
        }
    };

    scan(lo, hi);                                  // phase 1 -> per-lane d_ub

    float mx = fmaxf(fmaf(2.0f, best, psq), 0.0f);
#pragma unroll
    for (int o = 1; o < 64; o <<= 1) mx = fmaxf(mx, __shfl_xor(mx, o));
    const float md = sqrtf(mx);                    // wave-uniform

    const int lT = __builtin_amdgcn_readfirstlane(binOf(xL - md));
    const int rT = __builtin_amdgcn_readfirstlane(binOf(xR + md));
    scan(bs[lT], lo);                              // phase 2 left delta
    scan(hi, bs[rT + 1]);                          // phase 2 right delta

    float s = sqrtf(fmaxf(fmaf(2.0f, best, psq), 0.0f));
#pragma unroll
    for (int o = 1; o < 64; o <<= 1) s += __shfl_xor(s, o);
    if (lane == 0)
        atomicAdd(out, s * (1.0f / (float)ROWS));
}

extern "C" void kernel_launch(void* const* d_in, const int* in_sizes, int n_in,
                              void* d_out, int out_size, void* d_ws, size_t ws_size,
                              hipStream_t stream) {
    const float* completed = (const float*)d_in[0];  // (8, 8192, 3)
    const float* partial   = (const float*)d_in[1];  // (8, 4096, 3)
    float* out = (float*)d_out;
    char*  ws  = (char*)d_ws;

    int*    cStart = (int*)ws;
    float4* cPk    = (float4*)(ws + OFF_CPK);
    float4* qPk    = (float4*)(ws + OFF_QPK);
    int*    hist   = (int*)(ws + OFF_HIST);

    pml_prepA<<<2 * B * SLICES, 256, 0, stream>>>(completed, partial, hist, out);
    pml_prepB<<<2 * B * SLICES, 256, 0, stream>>>(completed, partial, hist,
                                                  cStart, cPk, qPk);
    pml_main<<<MAIN_BLOCKS, QPB, 0, stream>>>(cStart, cPk, qPk, out);
}

// Round 9
// 121.351 us; speedup vs baseline: 2.1198x; 2.1198x over previous
//
#include <hip/hip_runtime.h>

// PartialMatchingLoss: mean over (b,m) of min_n ||partial[b,m] - completed[b,n]||
// B=8, M=4096 (partial), N=8192 (completed), D=3, fp32.
//
// R14: uniform fixed-window pruned scan + exact fallback.
// R12/R13 post-mortem: two-phase md = group-max d_ub is inflated by y/z-tail
// queries (phase-1 d_ub ~0.6 vs true 0.35) -> windows ~2000+, pruning ~2x,
// eaten by lane redundancy / occupancy collapse. New scheme:
//  K1 scan: block = 256 x-sorted queries, fixed window [kmin-6, kmax+6] bins,
//     split over 8 chunk-blocks (1024 one-wave blocks), R4's dense inner loop
//     (TP=4 queries/thread, LDS-broadcast candidates, min3 pairing).
//  K2 verify: d1^2 <= min(gapL,gapR)^2 vs scanned bin edges -> exact for
//     passing queries (bin-edge bound proven absmax-0 in R10-R13); sum them.
//     Failures (y/z-tail, ~150 expected) compacted per batch (cap 1024,
//     inline-scan overflow fallback keeps correctness at any rate).
//  K3 fail-scan: full-N chunked scan of failed queries (unconditionally exact).
//  K4 fail-reduce: min over chunks, sqrt, sum.
// Per-pair math identical to all passing rounds: f = 0.5||c||^2 - p.c (3 FMA),
// d = sqrt(max(2f + ||p||^2, 0)).

constexpr int B  = 8;
constexpr int N  = 8192;
constexpr int M  = 4096;
constexpr int NB = 256;
constexpr float XLO = -6.0f, XHI = 6.0f;      // N(0,1): no sample near +/-6
constexpr float BINW = (XHI - XLO) / NB;      // 0.046875, exact in binary
constexpr float BINV = (float)NB / (XHI - XLO);
constexpr int ROWS = B * M;                   // 32768
constexpr int SLICES = 8;
constexpr int W   = 6;                        // scan half-width in bins
constexpr int QPB = 256;                      // queries per scan group
constexpr int GROUPS = ROWS / QPB;            // 128
constexpr int GPB = M / QPB;                  // 16 groups per batch
constexpr int S4  = 8;                        // chunk-blocks per group
constexpr int MAXF = 1024;                    // fail cap per batch
constexpr int FCH  = 64;                      // fail-scan candidate chunks
constexpr float FMAX = 3.402823466e38f;

// ws: cStart | cPk | qPk | hist | kLR | fp4 | failN | failL | fp5
constexpr size_t OFF_CPK  = 16 * 1024;
constexpr size_t OFF_QPK  = OFF_CPK + (size_t)B * N * 16;
constexpr size_t OFF_HIST = OFF_QPK + (size_t)B * M * 16;
constexpr size_t OFF_KLR  = OFF_HIST + (size_t)128 * NB * 4;
constexpr size_t OFF_FP4  = OFF_KLR + 16 * 1024;
constexpr size_t OFF_FN   = OFF_FP4 + (size_t)S4 * ROWS * 4;
constexpr size_t OFF_FL   = OFF_FN + 1024;
constexpr size_t OFF_FP5  = OFF_FL + (size_t)B * MAXF * 4;

__device__ __forceinline__ int binOf(float x) {
    int k = (int)floorf((x - XLO) * BINV);    // v_cvt saturates on +/-inf
    return k < 0 ? 0 : (k > NB - 1 ? NB - 1 : k);
}

// ---- prepA: per-slice histogram (vectorized group loads) -------------------
__global__ __launch_bounds__(256) void pml_prepA(const float* __restrict__ completed,
                                                 const float* __restrict__ partial,
                                                 int* __restrict__ hist,
                                                 int* __restrict__ failN,
                                                 float* __restrict__ out) {
    __shared__ int cnt[NB];
    const int t     = threadIdx.x;
    const int role  = blockIdx.x >> 3;        // 0..15 = (b, set)
    const int slice = blockIdx.x & 7;
    const int b     = role >> 1;
    const bool isQ  = role & 1;
    const int ns    = (isQ ? M : N) / SLICES;
    const int ngr   = ns / 4;
    const float4* sv = (const float4*)((isQ ? partial + (size_t)b * M * 3
                                            : completed + (size_t)b * N * 3)
                                       + (size_t)slice * ns * 3);
    cnt[t] = 0;
    __syncthreads();
    for (int g = t; g < ngr; g += 256) {
        float4 a = sv[3*g], b4 = sv[3*g+1], c4 = sv[3*g+2];
        atomicAdd(&cnt[binOf(a.x)],  1);
        atomicAdd(&cnt[binOf(a.w)],  1);
        atomicAdd(&cnt[binOf(b4.z)], 1);
        atomicAdd(&cnt[binOf(c4.y)], 1);
    }
    __syncthreads();
    hist[(size_t)blockIdx.x * NB + t] = cnt[t];
    if (blockIdx.x == 0) {
        if (t == 0) out[0] = 0.0f;            // all sums are strictly later
        if (t < B) failN[t] = 0;
    }
}

// ---- prepB: scan + scatter own slice ---------------------------------------
__global__ __launch_bounds__(256) void pml_prepB(const float* __restrict__ completed,
                                                 const float* __restrict__ partial,
                                                 const int* __restrict__ hist,
                                                 int* __restrict__ cStart,
                                                 float4* __restrict__ cPk,
                                                 float4* __restrict__ qPk) {
    __shared__ int sc[NB];
    __shared__ int st[NB + 1];
    __shared__ int mybase[NB];
    __shared__ int cur[NB];
    const int t     = threadIdx.x;
    const int role  = blockIdx.x >> 3;
    const int slice = blockIdx.x & 7;
    const int b     = role >> 1;
    const bool isQ  = role & 1;
    const int ns    = (isQ ? M : N) / SLICES;
    const int ngr   = ns / 4;
    const float4* sv = (const float4*)((isQ ? partial + (size_t)b * M * 3
                                            : completed + (size_t)b * N * 3)
                                       + (size_t)slice * ns * 3);
    int tot = 0, pre = 0;
#pragma unroll
    for (int s = 0; s < SLICES; ++s) {
        int h = hist[(size_t)((role << 3) + s) * NB + t];
        tot += h;
        if (s < slice) pre += h;
    }
    sc[t] = tot;
    __syncthreads();
#pragma unroll
    for (int o = 1; o < NB; o <<= 1) {        // Hillis-Steele inclusive scan
        int v = sc[t];
        if (t >= o) v += sc[t - o];
        __syncthreads();
        sc[t] = v;
        __syncthreads();
    }
    st[t + 1] = sc[t];
    if (t == 0) st[0] = 0;
    __syncthreads();
    if (!isQ && slice == 0)
        for (int k = t; k <= NB; k += 256) cStart[b * (NB + 1) + k] = st[k];
    mybase[t] = st[t] + pre;
    cur[t] = 0;
    __syncthreads();

    float4* dst = isQ ? qPk + (size_t)b * M : cPk + (size_t)b * N;
    for (int g = t; g < ngr; g += 256) {
        float4 a = sv[3*g], b4 = sv[3*g+1], c4 = sv[3*g+2];
        float xs[4] = {a.x, a.w,  b4.z, c4.y};
        float ys[4] = {a.y, b4.x, b4.w, c4.z};
        float zs[4] = {a.z, b4.y, c4.x, c4.w};
#pragma unroll
        for (int u = 0; u < 4; ++u) {
            int k = binOf(xs[u]);
            int pos = mybase[k] + atomicAdd(&cur[k], 1);
            float q2 = xs[u]*xs[u] + ys[u]*ys[u] + zs[u]*zs[u];
            dst[pos] = make_float4(xs[u], ys[u], zs[u], isQ ? q2 : 0.5f * q2);
        }
    }
}

// ---- K1 scan: group window, chunk-split, dense inner loop ------------------
__global__ __launch_bounds__(64) void pml_scan(const int* __restrict__ cStart,
                                               const float4* __restrict__ cPk,
                                               const float4* __restrict__ qPk,
                                               int2* __restrict__ kLR,
                                               float* __restrict__ fp4) {
    __shared__ float4 cs[130];
    const int t = threadIdx.x;
    const int s = blockIdx.x;                 // chunk 0..S4-1
    const int g = blockIdx.y;                 // group 0..127
    const int b = g / GPB;
    const int qrow0 = b * M + (g % GPB) * QPB;

    const float4* qv = qPk + qrow0 + t * 4;
    float4 q0 = qv[0], q1 = qv[1], q2 = qv[2], q3 = qv[3];
    float nx[4] = {-q0.x, -q1.x, -q2.x, -q3.x};
    float ny[4] = {-q0.y, -q1.y, -q2.y, -q3.y};
    float nz[4] = {-q0.z, -q1.z, -q2.z, -q3.z};
    float fm[4] = {FMAX, FMAX, FMAX, FMAX};

    float xmn = fminf(fminf(q0.x, q1.x), fminf(q2.x, q3.x));
    float xmx = fmaxf(fmaxf(q0.x, q1.x), fmaxf(q2.x, q3.x));
#pragma unroll
    for (int o = 1; o < 64; o <<= 1) {
        xmn = fminf(xmn, __shfl_xor(xmn, o));
        xmx = fmaxf(xmx, __shfl_xor(xmx, o));
    }
    const int kL = max(binOf(xmn) - W, 0);
    const int kR = min(binOf(xmx) + W, NB - 1);
    const int* bs = cStart + b * (NB + 1);
    const int lo = bs[kL], hi = bs[kR + 1];
    if (s == 0 && t == 0) kLR[g] = make_int2(kL, kR);

    const int len = hi - lo;
    const int c0 = lo + len * s / S4;
    const int c1 = lo + len * (s + 1) / S4;
    const float4* cb = cPk + (size_t)b * N;

    for (int base = c0; base < c1; base += 128) {
        const int cnt = min(128, c1 - base);
        __syncthreads();
        for (int i = t; i < cnt; i += 64) cs[i] = cb[base + i];
        if (t == 0 && (cnt & 1)) cs[cnt] = make_float4(0.f, 0.f, 0.f, FMAX);
        __syncthreads();
        const int cp = cnt + (cnt & 1);
#pragma unroll 4
        for (int j = 0; j < cp; j += 2) {
            float4 ca = cs[j], cc = cs[j + 1];
#pragma unroll
            for (int p = 0; p < 4; ++p) {
                float f0 = fmaf(nx[p], ca.x, fmaf(ny[p], ca.y, fmaf(nz[p], ca.z, ca.w)));
                float f1 = fmaf(nx[p], cc.x, fmaf(ny[p], cc.y, fmaf(nz[p], cc.z, cc.w)));
                fm[p] = fminf(fm[p], fminf(f0, f1));   // v_min3_f32
            }
        }
    }
    ((float4*)(fp4 + (size_t)s * ROWS + qrow0))[t] =
        make_float4(fm[0], fm[1], fm[2], fm[3]);
}

// ---- K2 verify: exactness test, sum passes, append fails -------------------
__global__ __launch_bounds__(256) void pml_verify(const float* __restrict__ fp4,
                                                  const float4* __restrict__ qPk,
                                                  const int2* __restrict__ kLR,
                                                  const float4* __restrict__ cPk,
                                                  int* __restrict__ failN,
                                                  int* __restrict__ failL,
                                                  float* __restrict__ out) {
    const int t   = threadIdx.x;
    const int row = blockIdx.x * 256 + t;
    float m = FMAX;
#pragma unroll
    for (int s = 0; s < S4; ++s) m = fminf(m, fp4[(size_t)s * ROWS + row]);
    const float4 Q = qPk[row];
    const float d2 = fmaxf(fmaf(2.0f, m, Q.w), 0.0f);
    const int2 klr = kLR[row >> 8];
    const float gl = (klr.x == 0)      ? FMAX : Q.x - fmaf((float)klr.x, BINW, XLO);
    const float gr = (klr.y == NB - 1) ? FMAX : fmaf((float)(klr.y + 1), BINW, XLO) - Q.x;
    const float gm = fminf(gl, gr);
    const int b = row >> 12;

    float sv = 0.0f;
    if (d2 <= gm * gm) {
        sv = sqrtf(d2);                       // exact: unscanned all farther than gm
    } else {
        int pos = atomicAdd(&failN[b], 1);
        if (pos < MAXF) {
            failL[b * MAXF + pos] = row;      // resolved by pml_fail
        } else {                              // overflow fallback: inline full scan
            const float4* cb = cPk + (size_t)b * N;
            float px = -Q.x, py = -Q.y, pz = -Q.z, bf = FMAX;
            for (int i = 0; i < N; ++i) {
                float4 c = cb[i];
                bf = fminf(bf, fmaf(px, c.x, fmaf(py, c.y, fmaf(pz, c.z, c.w))));
            }
            sv = sqrtf(fmaxf(fmaf(2.0f, bf, Q.w), 0.0f));
        }
    }
#pragma unroll
    for (int off = 32; off > 0; off >>= 1) sv += __shfl_down(sv, off);
    __shared__ float red[4];
    const int lane = t & 63, wid = t >> 6;
    if (lane == 0) red[wid] = sv;
    __syncthreads();
    if (t == 0)
        atomicAdd(out, (red[0] + red[1] + red[2] + red[3]) * (1.0f / (float)ROWS));
}

// ---- K3 fail-scan: full-N chunked scan of failed queries (exact) -----------
__global__ __launch_bounds__(64) void pml_fail(const int* __restrict__ failN,
                                               const int* __restrict__ failL,
                                               const float4* __restrict__ cPk,
                                               const float4* __restrict__ qPk,
                                               float* __restrict__ fp5) {
    const int t  = threadIdx.x;
    const int c  = blockIdx.x;                // candidate chunk 0..FCH-1
    const int qb = blockIdx.y;                // slot block 0..MAXF/64-1
    const int b  = blockIdx.z;
    const int nF = min(failN[b], MAXF);
    if (qb * 64 >= nF) return;
    const int slot = qb * 64 + t;
    const int row  = failL[b * MAXF + min(slot, nF - 1)];
    const float4 Q = qPk[row];
    const float px = -Q.x, py = -Q.y, pz = -Q.z;
    const float4* cb = cPk + (size_t)b * N;
    const int c0 = c * (N / FCH), c1 = c0 + (N / FCH);
    float fm = FMAX;
#pragma unroll 4
    for (int j = c0; j < c1; j += 2) {        // uniform addr -> broadcast loads
        float4 ca = cb[j], cc = cb[j + 1];
        float f0 = fmaf(px, ca.x, fmaf(py, ca.y, fmaf(pz, ca.z, ca.w)));
        float f1 = fmaf(px, cc.x, fmaf(py, cc.y, fmaf(pz, cc.z, cc.w)));
        fm = fminf(fm, fminf(f0, f1));
    }
    fp5[((size_t)c * B + b) * MAXF + slot] = fm;
}

// ---- K4 fail-reduce --------------------------------------------------------
__global__ __launch_bounds__(256) void pml_failred(const int* __restrict__ failN,
                                                   const int* __restrict__ failL,
                                                   const float4* __restrict__ qPk,
                                                   const float* __restrict__ fp5,
                                                   float* __restrict__ out) {
    const int t   = threadIdx.x;
    const int idx = blockIdx.x * 256 + t;     // 0..8191
    const int b   = idx >> 10;
    const int slot = idx & (MAXF - 1);
    const int nF  = min(failN[b], MAXF);
    float sv = 0.0f;
    if (slot < nF) {
        float m = FMAX;
#pragma unroll 8
        for (int c = 0; c < FCH; ++c)
            m = fminf(m, fp5[((size_t)c * B + b) * MAXF + slot]);
        const int row = failL[b * MAXF + slot];
        sv = sqrtf(fmaxf(fmaf(2.0f, m, qPk[row].w), 0.0f));
    }
#pragma unroll
    for (int off = 32; off > 0; off >>= 1) sv += __shfl_down(sv, off);
    __shared__ float red[4];
    const int lane = t & 63, wid = t >> 6;
    if (lane == 0) red[wid] = sv;
    __syncthreads();
    if (t == 0)
        atomicAdd(out, (red[0] + red[1] + red[2] + red[3]) * (1.0f / (float)ROWS));
}

extern "C" void kernel_launch(void* const* d_in, const int* in_sizes, int n_in,
                              void* d_out, int out_size, void* d_ws, size_t ws_size,
                              hipStream_t stream) {
    const float* completed = (const float*)d_in[0];  // (8, 8192, 3)
    const float* partial   = (const float*)d_in[1];  // (8, 4096, 3)
    float* out = (float*)d_out;
    char*  ws  = (char*)d_ws;

    int*    cStart = (int*)ws;
    float4* cPk    = (float4*)(ws + OFF_CPK);
    float4* qPk    = (float4*)(ws + OFF_QPK);
    int*    hist   = (int*)(ws + OFF_HIST);
    int2*   kLR    = (int2*)(ws + OFF_KLR);
    float*  fp4    = (float*)(ws + OFF_FP4);
    int*    failN  = (int*)(ws + OFF_FN);
    int*    failL  = (int*)(ws + OFF_FL);
    float*  fp5    = (float*)(ws + OFF_FP5);

    pml_prepA<<<2 * B * SLICES, 256, 0, stream>>>(completed, partial, hist, failN, out);
    pml_prepB<<<2 * B * SLICES, 256, 0, stream>>>(completed, partial, hist,
                                                  cStart, cPk, qPk);
    pml_scan<<<dim3(S4, GROUPS), 64, 0, stream>>>(cStart, cPk, qPk, kLR, fp4);
    pml_verify<<<ROWS / 256, 256, 0, stream>>>(fp4, qPk, kLR, cPk, failN, failL, out);
    pml_fail<<<dim3(FCH, MAXF / 64, B), 64, 0, stream>>>(failN, failL, cPk, qPk, fp5);
    pml_failred<<<(B * MAXF) / 256, 256, 0, stream>>>(failN, failL, qPk, fp5, out);
}